// Round 15
// baseline (53.461 us; speedup 1.0000x reference)
//
#include <hip/hip_runtime.h>

#define OUT_F 16384
#define IN_F  4096
#define GS    128
#define NG    32
#define KT    64           // ints per row per K-tile (= GS/2)
#define NTW   16           // tiles per wave (quarter-K: 1024 ints / KT)

typedef __attribute__((ext_vector_type(4)))  int    int4v;
typedef __attribute__((ext_vector_type(4)))  float  float4v;
typedef __attribute__((ext_vector_type(8)))  short  short8v;
typedef __attribute__((ext_vector_type(16))) float  floatx16;

// f32 -> bf16 round-to-nearest-even (bit-level)
static __device__ __forceinline__ short f32_bf16_rne(float f) {
    unsigned u = __float_as_uint(f);
    u += 0x7FFFu + ((u >> 16) & 1u);
    return (short)(u >> 16);
}

// HBM -> LDS direct, 16B/lane; dest = wave-uniform base + lane*16 (HW rule)
#define GLOAD_LDS16(gp, lp)                                                    \
    __builtin_amdgcn_global_load_lds(                                          \
        (const __attribute__((address_space(1))) void*)(gp),                   \
        (__attribute__((address_space(3))) void*)(lp), 16, 0, 0)

// ---------------------------------------------------------------------------
// Single kernel (xfrag pre-kernel eliminated): 512 blocks x 4 waves ->
// 64 KB LDS -> 2 blocks/CU -> 8 waves/CU. Wave wv owns 32 rows x quarter-K:
// 16 tiles of [32 rows][64 ints].
// Per tile: 8x gload_lds weights (source pre-swizzled u=(l&15)^(row&15)) +
// 8x float4 x-loads in B-fragment order (L2-hot, lane l -> row ll, k-half hl),
// both prefetched ONE TILE AHEAD (parity register sets), counted vmcnt(16).
// x converted f32->bf16 RNE at consume time (loads landed a tile ago).
// No main-loop barriers. Race-free epilogue (r14): each wave writes partials
// only in its own LDS region; wave 0 reduces + XOR-transpose + bias store.
// ---------------------------------------------------------------------------
__global__ __launch_bounds__(256) void int4linear_mfma(
    const int* __restrict__ w, const float* __restrict__ scales,
    const float* __restrict__ bias, const float* __restrict__ x,
    float* __restrict__ out)
{
    __shared__ int lds[16384];         // 64 KB: wave wv owns [wv*4096, +4096)

    const int tid = threadIdx.x;
    const int wv  = tid >> 6;          // 0..3
    const int l   = tid & 63;
    const int ll  = l & 31;
    const int hl  = l >> 5;
    const int o_base = blockIdx.x * 32;

    floatx16 acc = {};
    int* mylds = lds + wv * 4096;

    // staging: instr j covers rows 4j..4j+3 (lane l -> row 4j + (l>>4),
    // source unit (l&15) ^ (row&15)); linear LDS dest j*1KB.
    int goff[8];
#pragma unroll
    for (int j = 0; j < 8; ++j) {
        int r = 4 * j + (l >> 4);
        goff[j] = (o_base + r) * IN_F + wv * 1024 + (((l & 15) ^ (r & 15)) << 2);
    }

    // this wave's 8 group-scales for row ll (quarter-K = 8 groups)
    float scv[8];
    {
        const float* sp = scales + (size_t)(o_base + ll) * NG + wv * 8;
#pragma unroll
        for (int j = 0; j < 2; ++j) {
            float4v v = *(const float4v*)(sp + 4 * j);
            scv[4 * j + 0] = v[0]; scv[4 * j + 1] = v[1];
            scv[4 * j + 2] = v[2]; scv[4 * j + 3] = v[3];
        }
    }

    // x in B-fragment order: lane l reads x[b=ll][k = wv*1024 + t*64 + ch*16
    // + hl*8 + i], i=0..7 -> two float4. Lanes l and l+32 cover one 64B line.
    const float* xp = x + (size_t)ll * IN_F + wv * 1024 + hl * 8;

    float4v pfxA[8], pfxB[8];          // parity sets, statically indexed

    // ---- prologue: stage tile 0 weights + tile 0 x ----
#pragma unroll
    for (int j = 0; j < 8; ++j)
        GLOAD_LDS16(w + goff[j], &mylds[j * 256]);
#pragma unroll
    for (int ch = 0; ch < 4; ++ch) {
        pfxA[2 * ch]     = *(const float4v*)(xp + ch * 16);
        pfxA[2 * ch + 1] = *(const float4v*)(xp + ch * 16 + 4);
    }

#pragma unroll
    for (int t = 0; t < NTW; ++t) {
        const int rbuf = (t & 1) * 2048;
        const int wbuf = ((t + 1) & 1) * 2048;

        if (t + 1 < NTW) {
            // next tile's weight staging + x prefetch (into the other set)
#pragma unroll
            for (int j = 0; j < 8; ++j)
                GLOAD_LDS16(w + goff[j] + (t + 1) * KT, &mylds[wbuf + j * 256]);
#pragma unroll
            for (int ch = 0; ch < 4; ++ch) {
                const float* px = xp + (t + 1) * 64 + ch * 16;
                float4v f0 = *(const float4v*)px;
                float4v f1 = *(const float4v*)(px + 4);
                if (t & 1) { pfxA[2 * ch] = f0; pfxA[2 * ch + 1] = f1; }
                else       { pfxB[2 * ch] = f0; pfxB[2 * ch + 1] = f1; }
            }
            // drain exactly last iteration's 16 ops (issued a full tile ago);
            // keep the newest 16 (staging t+1 + x t+1) in flight.
            asm volatile("s_waitcnt vmcnt(16)" ::: "memory");
        } else {
            asm volatile("s_waitcnt vmcnt(0)" ::: "memory");
        }
        __builtin_amdgcn_sched_barrier(0);

        // tile t spans half a scale group: group = t>>1 (KT = GS/2)
        const float sc = scv[t >> 1];

#pragma unroll
        for (int ch = 0; ch < 4; ++ch) {
            const int u0 = ch * 4 + hl * 2;   // logical 16B-unit 0..15
            const int4v qa = *(const int4v*)&mylds[rbuf + ll * 64 + (((u0    ) ^ (ll & 15)) << 2)];
            const int4v qb = *(const int4v*)&mylds[rbuf + ll * 64 + (((u0 + 1) ^ (ll & 15)) << 2)];

            const float4v x0 = (t & 1) ? pfxB[2 * ch]     : pfxA[2 * ch];
            const float4v x1 = (t & 1) ? pfxB[2 * ch + 1] : pfxA[2 * ch + 1];

            short8v bf;
            bf[0] = f32_bf16_rne(x0[0]); bf[1] = f32_bf16_rne(x0[1]);
            bf[2] = f32_bf16_rne(x0[2]); bf[3] = f32_bf16_rne(x0[3]);
            bf[4] = f32_bf16_rne(x1[0]); bf[5] = f32_bf16_rne(x1[1]);
            bf[6] = f32_bf16_rne(x1[2]); bf[7] = f32_bf16_rne(x1[3]);

            short8v af;
            af[0] = f32_bf16_rne((float)qa[0] * sc);
            af[1] = f32_bf16_rne((float)qa[1] * sc);
            af[2] = f32_bf16_rne((float)qa[2] * sc);
            af[3] = f32_bf16_rne((float)qa[3] * sc);
            af[4] = f32_bf16_rne((float)qb[0] * sc);
            af[5] = f32_bf16_rne((float)qb[1] * sc);
            af[6] = f32_bf16_rne((float)qb[2] * sc);
            af[7] = f32_bf16_rne((float)qb[3] * sc);

            acc = __builtin_amdgcn_mfma_f32_32x32x16_bf16(af, bf, acc, 0, 0, 0);
        }
    }

    // ---- RACE-FREE epilogue (verified r14): partials stay in-region -------
    if (wv > 0) {
        float* myred = (float*)lds + wv * 4096;
#pragma unroll
        for (int r = 0; r < 16; ++r)
            myred[l * 16 + r] = acc[r];
    }
    __syncthreads();
    if (wv == 0) {
        const float* lfp = (const float*)lds;
#pragma unroll
        for (int r = 0; r < 16; ++r)
            acc[r] += lfp[4096 + l * 16 + r] + lfp[8192 + l * 16 + r]
                    + lfp[12288 + l * 16 + r];

        float* lf = (float*)lds + 3072;   // wave 0's own region
#pragma unroll
        for (int r = 0; r < 16; ++r) {
            // C/D layout (verified): b = lane&31, o = (r&3)+8*(r>>2)+4*(lane>>5)
            int o = (r & 3) + 8 * (r >> 2) + 4 * hl;
            lf[o * 32 + (ll ^ o)] = acc[r]; // conflict-free (XOR bijection)
        }
        asm volatile("s_waitcnt lgkmcnt(0)" ::: "memory");
        __builtin_amdgcn_sched_barrier(0);

        const float bv = bias[o_base + ll];
#pragma unroll
        for (int i = 0; i < 16; ++i) {
            int b = 2 * i + hl;
            float v = lf[ll * 32 + (b ^ ll)];              // conflict-free
            out[(size_t)b * OUT_F + o_base + ll] = v + bv; // 128B-coalesced
        }
    }
}

extern "C" void kernel_launch(void* const* d_in, const int* in_sizes, int n_in,
                              void* d_out, int out_size, void* d_ws, size_t ws_size,
                              hipStream_t stream) {
    const float* x      = (const float*)d_in[0];
    const int*   w      = (const int*)d_in[1];
    const float* scales = (const float*)d_in[2];
    const float* bias   = (const float*)d_in[3];
    float*       out    = (float*)d_out;
    (void)d_ws; (void)ws_size;

    hipLaunchKernelGGL(int4linear_mfma, dim3(OUT_F / 32), dim3(256), 0, stream,
                       w, scales, bias, x, out);
}

// Round 17
// 49.495 us; speedup vs baseline: 1.0801x; 1.0801x over previous
//
#include <hip/hip_runtime.h>

#define OUT_F 16384
#define IN_F  4096
#define GS    128
#define NG    32
#define KT    64           // ints per row per K-tile (= GS/2)
#define NTW   16           // tiles per wave (quarter-K: 1024 ints / KT)

typedef __attribute__((ext_vector_type(4)))  int    int4v;
typedef __attribute__((ext_vector_type(4)))  short  short4v;
typedef __attribute__((ext_vector_type(4)))  float  float4v;
typedef __attribute__((ext_vector_type(8)))  short  short8v;
typedef __attribute__((ext_vector_type(16))) float  floatx16;

// f32 -> bf16 round-to-nearest-even (bit-level)
static __device__ __forceinline__ short f32_bf16_rne(float f) {
    unsigned u = __float_as_uint(f);
    u += 0x7FFFu + ((u >> 16) & 1u);
    return (short)(u >> 16);
}

// HBM -> LDS direct, 16B/lane; dest = wave-uniform base + lane*16 (HW rule)
#define GLOAD_LDS16(gp, lp)                                                    \
    __builtin_amdgcn_global_load_lds(                                          \
        (const __attribute__((address_space(1))) void*)(gp),                   \
        (__attribute__((address_space(3))) void*)(lp), 16, 0, 0)

// ---------------------------------------------------------------------------
// Pre-kernel (compact): x B-fragments in MFMA layout, 4 elems/thread.
// Mapping identical to the verified scalar version: for xf index g,
//   i = g&7, l = (g>>3)&63, c = g>>9, b = l&31, k = c*16 + (l>>5)*8 + i.
// Thread t handles g = 4t..4t+3: i base in {0,4}, same l,c -> one float4
// read (16B-aligned) + one short4 write.
// ---------------------------------------------------------------------------
__global__ void xfrag_kernel(const float* __restrict__ x, short* __restrict__ xf) {
    int t = blockIdx.x * blockDim.x + threadIdx.x;  // 0..32767
    int base = t * 4;
    int i = base & 7;           // 0 or 4
    int l = (base >> 3) & 63;
    int c = base >> 9;
    int b = l & 31;
    int k = c * 16 + (l >> 5) * 8 + i;
    float4v v = *(const float4v*)(x + (size_t)b * IN_F + k);
    short4v s;
    s[0] = f32_bf16_rne(v[0]); s[1] = f32_bf16_rne(v[1]);
    s[2] = f32_bf16_rne(v[2]); s[3] = f32_bf16_rne(v[3]);
    *(short4v*)(xf + base) = s;
}

// ---------------------------------------------------------------------------
// Main kernel (round-14 verbatim, verified 50.57 us): 512 blocks x 4 waves ->
// 64 KB LDS -> 2 blocks/CU -> 8 waves/CU. Wave wv owns 32 rows x quarter-K:
// 16 tiles of [32 rows][64 ints].
// Per tile: 8x gload_lds (source pre-swizzled u=(l&15)^(row&15)), xf
// prefetched ONE TILE AHEAD (bfrA/bfrB parity), counted vmcnt(12).
// No main-loop barriers. Race-free epilogue: each wave writes partials ONLY
// inside its own 16 KB region; wave 0 reduces after the single barrier.
// ---------------------------------------------------------------------------
__global__ __launch_bounds__(256) void int4linear_mfma(
    const int* __restrict__ w, const float* __restrict__ scales,
    const float* __restrict__ bias, const short* __restrict__ xf,
    float* __restrict__ out)
{
    __shared__ int lds[16384];         // 64 KB: wave wv owns [wv*4096, +4096)

    const int tid = threadIdx.x;
    const int wv  = tid >> 6;          // 0..3
    const int l   = tid & 63;
    const int ll  = l & 31;
    const int hl  = l >> 5;
    const int o_base = blockIdx.x * 32;

    floatx16 acc = {};
    int* mylds = lds + wv * 4096;

    // staging: instr j covers rows 4j..4j+3 (lane l -> row 4j + (l>>4),
    // source unit (l&15) ^ (row&15)); linear LDS dest j*1KB.
    int goff[8];
#pragma unroll
    for (int j = 0; j < 8; ++j) {
        int r = 4 * j + (l >> 4);
        goff[j] = (o_base + r) * IN_F + wv * 1024 + (((l & 15) ^ (r & 15)) << 2);
    }

    // this wave's 8 group-scales for row ll (quarter-K = 8 groups)
    float scv[8];
    {
        const float* sp = scales + (size_t)(o_base + ll) * NG + wv * 8;
#pragma unroll
        for (int j = 0; j < 2; ++j) {
            float4v v = *(const float4v*)(sp + 4 * j);
            scv[4 * j + 0] = v[0]; scv[4 * j + 1] = v[1];
            scv[4 * j + 2] = v[2]; scv[4 * j + 3] = v[3];
        }
    }

    const short* xfw = xf + (size_t)(wv * 64) * 512;   // wave's chunk base

    short8v bfrA[4], bfrB[4];

    // ---- prologue: stage tile 0 + xf tile 0 ----
#pragma unroll
    for (int j = 0; j < 8; ++j)
        GLOAD_LDS16(w + goff[j], &mylds[j * 256]);
#pragma unroll
    for (int ch = 0; ch < 4; ++ch)
        bfrA[ch] = *(const short8v*)(xfw + (size_t)ch * 512 + l * 8);

#pragma unroll
    for (int t = 0; t < NTW; ++t) {
        const int rbuf = (t & 1) * 2048;
        const int wbuf = ((t + 1) & 1) * 2048;

        if (t + 1 < NTW) {
            // next tile's staging, then next tile's xf (prefetch)
#pragma unroll
            for (int j = 0; j < 8; ++j)
                GLOAD_LDS16(w + goff[j] + (t + 1) * KT, &mylds[wbuf + j * 256]);
#pragma unroll
            for (int ch = 0; ch < 4; ++ch) {
                short8v v = *(const short8v*)(xfw + (size_t)((t + 1) * 4 + ch) * 512 + l * 8);
                if (t & 1) bfrA[ch] = v; else bfrB[ch] = v;
            }
            // drain exactly last iteration's 12 ops (issued a full tile ago);
            // keep the newest 12 (staging t+1 + xf t+1) in flight.
            asm volatile("s_waitcnt vmcnt(12)" ::: "memory");
        } else {
            asm volatile("s_waitcnt vmcnt(0)" ::: "memory");
        }
        __builtin_amdgcn_sched_barrier(0);

        // tile t spans half a scale group: group = t>>1 (KT = GS/2)
        const float sc = scv[t >> 1];

#pragma unroll
        for (int ch = 0; ch < 4; ++ch) {
            const int u0 = ch * 4 + hl * 2;   // logical 16B-unit 0..15
            const int4v qa = *(const int4v*)&mylds[rbuf + ll * 64 + (((u0    ) ^ (ll & 15)) << 2)];
            const int4v qb = *(const int4v*)&mylds[rbuf + ll * 64 + (((u0 + 1) ^ (ll & 15)) << 2)];
            const short8v bf = (t & 1) ? bfrB[ch] : bfrA[ch];

            short8v af;
            af[0] = f32_bf16_rne((float)qa[0] * sc);
            af[1] = f32_bf16_rne((float)qa[1] * sc);
            af[2] = f32_bf16_rne((float)qa[2] * sc);
            af[3] = f32_bf16_rne((float)qa[3] * sc);
            af[4] = f32_bf16_rne((float)qb[0] * sc);
            af[5] = f32_bf16_rne((float)qb[1] * sc);
            af[6] = f32_bf16_rne((float)qb[2] * sc);
            af[7] = f32_bf16_rne((float)qb[3] * sc);

            acc = __builtin_amdgcn_mfma_f32_32x32x16_bf16(af, bf, acc, 0, 0, 0);
        }
    }

    // ---- RACE-FREE epilogue: partials stay inside each wave's own region ---
    if (wv > 0) {
        float* myred = (float*)lds + wv * 4096;
#pragma unroll
        for (int r = 0; r < 16; ++r)
            myred[l * 16 + r] = acc[r];
    }
    __syncthreads();
    if (wv == 0) {
        const float* lfp = (const float*)lds;
#pragma unroll
        for (int r = 0; r < 16; ++r)
            acc[r] += lfp[4096 + l * 16 + r] + lfp[8192 + l * 16 + r]
                    + lfp[12288 + l * 16 + r];

        float* lf = (float*)lds + 3072;   // wave 0's own region
#pragma unroll
        for (int r = 0; r < 16; ++r) {
            // C/D layout (verified): b = lane&31, o = (r&3)+8*(r>>2)+4*(lane>>5)
            int o = (r & 3) + 8 * (r >> 2) + 4 * hl;
            lf[o * 32 + (ll ^ o)] = acc[r]; // conflict-free (XOR bijection)
        }
        asm volatile("s_waitcnt lgkmcnt(0)" ::: "memory");
        __builtin_amdgcn_sched_barrier(0);

        const float bv = bias[o_base + ll];
#pragma unroll
        for (int i = 0; i < 16; ++i) {
            int b = 2 * i + hl;
            float v = lf[ll * 32 + (b ^ ll)];              // conflict-free
            out[(size_t)b * OUT_F + o_base + ll] = v + bv; // 128B-coalesced
        }
    }
}

extern "C" void kernel_launch(void* const* d_in, const int* in_sizes, int n_in,
                              void* d_out, int out_size, void* d_ws, size_t ws_size,
                              hipStream_t stream) {
    const float* x      = (const float*)d_in[0];
    const int*   w      = (const int*)d_in[1];
    const float* scales = (const float*)d_in[2];
    const float* bias   = (const float*)d_in[3];
    float*       out    = (float*)d_out;
    short*       xfrag  = (short*)d_ws;  // 256 KB fragment buffer

    hipLaunchKernelGGL(xfrag_kernel, dim3(128), dim3(256), 0, stream, x, xfrag);
    hipLaunchKernelGGL(int4linear_mfma, dim3(OUT_F / 32), dim3(256), 0, stream,
                       w, scales, bias, xfrag, out);
}